// Round 4
// baseline (77.853 us; speedup 1.0000x reference)
//
#include <hip/hip_runtime.h>
#include <hip/hip_bf16.h>
#include <math.h>

typedef __attribute__((ext_vector_type(4))) float f32x4;
typedef __attribute__((ext_vector_type(8))) short bf16x8;

#define NB    64
#define LQ    32
#define LDOC  256
#define HDIM  768
#define DDIM  128
#define NTOK_Q (NB * LQ)        // 2048
#define NTOK_D (NB * LDOC)      // 16384
#define NTOK   (NTOK_Q + NTOK_D) // 18432

// ws layout (bytes):
#define WS_OFF_W    0           // Wbf   : 128*768 bf16   (196608)
#define WS_OFF_MASK 196608      // maskT : 64*16 ushort (2KB)
#define WS_OFF_QN   212992      // Qn    : 2048*128 bf16
#define WS_OFF_DN   737280      // Dn    : 16384*128 bf16

__device__ inline short f2bf(float f) {
    unsigned u = __float_as_uint(f);
    u = (u + 0x7fffu + ((u >> 16) & 1u)) >> 16;   // RNE
    return (short)u;
}

// ---------------------------------------------------------------------------
// prep: blocks 0..95 convert W fp32->bf16; block 96 builds bit-transposed mask.
__global__ void prep(const float* __restrict__ W, short* __restrict__ Wbf,
                     const unsigned char* __restrict__ mraw,
                     unsigned short* __restrict__ maskT) {
    if (blockIdx.x < 96) {
        int i = blockIdx.x * 256 + threadIdx.x;
        float4 v = *(const float4*)(W + (size_t)i * 4);
        short4 o;
        o.x = f2bf(v.x); o.y = f2bf(v.y); o.z = f2bf(v.z); o.w = f2bf(v.w);
        *(short4*)(Wbf + (size_t)i * 4) = o;
        return;
    }
    __shared__ int dword_ok_s;
    if (threadIdx.x == 0) dword_ok_s = 1;
    __syncthreads();
    const unsigned* dw = (const unsigned*)mraw;
    int ok = 1;
    for (int i = threadIdx.x; i < 4096; i += 256) {   // first 16KB: safe both ways
        unsigned v = dw[i];
        if (!(v == 0u || v == 1u || v == 0x3F800000u)) ok = 0;
    }
    if (!ok) atomicAnd(&dword_ok_s, 0);
    __syncthreads();
    const int isdw = dword_ok_s;
    for (int w = threadIdx.x; w < 1024; w += 256) {   // word w: c=w>>4, lane-col=w&15
        const int c = w >> 4, lcc = w & 15;
        unsigned bits = 0;
        if (isdw) {
            for (int nt = 0; nt < 16; ++nt)
                bits |= (dw[c * 256 + nt * 16 + lcc] ? 1u : 0u) << nt;
        } else {
            for (int nt = 0; nt < 16; ++nt)
                bits |= (mraw[c * 256 + nt * 16 + lcc] ? 1u : 0u) << nt;
        }
        maskT[w] = (unsigned short)bits;
    }
}

// ---------------------------------------------------------------------------
// Projection + L2 norm v4: barrier-free streaming. Wave = 16 rows x 64 cols,
// full K=768 unrolled; A per-lane from global with depth-4 register prefetch;
// B (Wbf) from L2. Waves (2p, 2p+1) of a block = the two N-halves of a panel;
// one LDS exchange at the end combines sum-of-squares for the row norm.
__global__ __launch_bounds__(256, 4)
void proj_norm(const float* __restrict__ Qh, const float* __restrict__ Dh,
               const short* __restrict__ Wbf,
               short* __restrict__ Qn, short* __restrict__ Dn) {
    const int lane = threadIdx.x & 63;
    const int wave = threadIdx.x >> 6;          // 0..3
    const int g    = lane >> 4;                 // k-subslice / row-group
    const int lc   = lane & 15;                 // A-row / B-col / C-col
    const int panel = blockIdx.x * 2 + (wave >> 1);   // 16-row panel, 0..1151
    const int nh    = wave & 1;                       // which 64-col half

    const int row = panel * 16 + lc;
    const float* srcRow = (row < NTOK_Q) ? Qh + (size_t)row * HDIM
                                         : Dh + (size_t)(row - NTOK_Q) * HDIM;
    const short* wb0 = Wbf + (size_t)(nh * 64 + lc) * HDIM;   // nt stride = 16*HDIM

    f32x4 acc[4];
#pragma unroll
    for (int nt = 0; nt < 4; ++nt) acc[nt] = (f32x4){0.f, 0.f, 0.f, 0.f};

    // depth-4 rotating A prefetch (static indices via full unroll)
    float4 pa[4], pb[4];
#pragma unroll
    for (int s = 0; s < 4; ++s) {
        pa[s] = *(const float4*)(srcRow + s * 32 + g * 8);
        pb[s] = *(const float4*)(srcRow + s * 32 + g * 8 + 4);
    }

#pragma unroll
    for (int s = 0; s < 24; ++s) {
        const float4 a0 = pa[s & 3], a1 = pb[s & 3];
        if (s + 4 < 24) {
            pa[s & 3] = *(const float4*)(srcRow + (s + 4) * 32 + g * 8);
            pb[s & 3] = *(const float4*)(srcRow + (s + 4) * 32 + g * 8 + 4);
        }
        bf16x8 af;
        af[0] = f2bf(a0.x); af[1] = f2bf(a0.y); af[2] = f2bf(a0.z); af[3] = f2bf(a0.w);
        af[4] = f2bf(a1.x); af[5] = f2bf(a1.y); af[6] = f2bf(a1.z); af[7] = f2bf(a1.w);
        const int ko = s * 32 + g * 8;
#pragma unroll
        for (int nt = 0; nt < 4; ++nt) {
            bf16x8 bv = *(const bf16x8*)(wb0 + (size_t)nt * 16 * HDIM + ko);
            acc[nt] = __builtin_amdgcn_mfma_f32_16x16x32_bf16(af, bv, acc[nt], 0, 0, 0);
        }
    }

    // per-row sum of squares for this half; combine with partner wave via LDS
    __shared__ float norms[4][16];
    float p[4];
#pragma unroll
    for (int i = 0; i < 4; ++i) {
        float s = 0.f;
#pragma unroll
        for (int nt = 0; nt < 4; ++nt) s += acc[nt][i] * acc[nt][i];
        s += __shfl_xor(s, 1);
        s += __shfl_xor(s, 2);
        s += __shfl_xor(s, 4);
        s += __shfl_xor(s, 8);
        p[i] = s;
    }
    if (lc == 0) {
#pragma unroll
        for (int i = 0; i < 4; ++i) norms[wave][g * 4 + i] = p[i];
    }
    __syncthreads();

#pragma unroll
    for (int i = 0; i < 4; ++i) {
        const int rloc = g * 4 + i;                 // C row = (lane>>4)*4 + i
        const float tot = norms[wave][rloc] + norms[wave ^ 1][rloc];
        const float inv = 1.f / fmaxf(sqrtf(tot), 1e-12f);
        const int r = panel * 16 + rloc;
        short* dst = (r < NTOK_Q) ? (Qn + (size_t)r * DDIM)
                                  : (Dn + (size_t)(r - NTOK_Q) * DDIM);
#pragma unroll
        for (int nt = 0; nt < 4; ++nt)
            dst[nh * 64 + nt * 16 + lc] = f2bf(acc[nt][i] * inv);
    }
}

// ---------------------------------------------------------------------------
// MaxSim: block = (c, 8 b's) = 256 q-rows x 256 n. D[c] staged once in LDS
// (64KB) via global_load_lds with pre-swizzled source; 4 waves x 256 MFMA.
__global__ __launch_bounds__(256)
void maxsim(const short* __restrict__ Qn, const short* __restrict__ Dn,
            const unsigned short* __restrict__ maskT, float* __restrict__ out) {
    const int x  = blockIdx.x & 7;            // XCD (perf heuristic only)
    const int m8 = (blockIdx.x >> 3) & 7;
    const int bg = blockIdx.x >> 6;           // b-group (8 b's)
    const int c  = x * 8 + m8;                // all 8 bg's of a c on one XCD

    const int wave = threadIdx.x >> 6;
    const int lane = threadIdx.x & 63;
    const int g = lane >> 4, lc = lane & 15;

    __shared__ alignas(16) short Ds[LDOC * DDIM];   // 64KB, swizzled layout

    const short* dsrc = Dn + (size_t)c * LDOC * DDIM;
#pragma unroll
    for (int i = 0; i < 16; ++i) {
        const int slot = wave * 1024 + i * 64 + lane;          // 16B units
        const int row = slot >> 4, c16 = slot & 15;
        const short* gaddr = dsrc + row * DDIM + ((c16 ^ (row & 15)) * 8);
        __builtin_amdgcn_global_load_lds(
            (const __attribute__((address_space(1))) unsigned int*)gaddr,
            (__attribute__((address_space(3))) unsigned int*)(Ds + (size_t)(wave * 1024 + i * 64) * 8),
            16, 0, 0);
    }

    bf16x8 qf[4][4];
    const int qrow0 = bg * 256 + wave * 64;
#pragma unroll
    for (int m = 0; m < 4; ++m) {
        const short* qb = Qn + (size_t)(qrow0 + m * 16 + lc) * DDIM;
#pragma unroll
        for (int ks = 0; ks < 4; ++ks)
            qf[m][ks] = *(const bf16x8*)(qb + ks * 32 + g * 8);
    }

    const unsigned mbits = maskT[c * 16 + lc];    // bit nt = mask[c][nt*16+lc]

    __syncthreads();   // drains vmcnt (staging + q loads) then barrier

    float rmax[4][4];
#pragma unroll
    for (int m = 0; m < 4; ++m)
#pragma unroll
        for (int i = 0; i < 4; ++i) rmax[m][i] = -INFINITY;

    for (int nt = 0; nt < 16; ++nt) {
        bf16x8 bf[4];
        const int row = nt * 16 + lc;
#pragma unroll
        for (int ks = 0; ks < 4; ++ks) {
            const int c16 = (ks * 4 + g) ^ lc;     // read-side swizzle (matches source)
            bf[ks] = *(const bf16x8*)(Ds + row * DDIM + c16 * 8);
        }
        const bool on = (mbits >> nt) & 1;         // n = nt*16+lc == C-col lc
#pragma unroll
        for (int m = 0; m < 4; ++m) {
            f32x4 acc = (f32x4){0.f, 0.f, 0.f, 0.f};
#pragma unroll
            for (int ks = 0; ks < 4; ++ks)
                acc = __builtin_amdgcn_mfma_f32_16x16x32_bf16(qf[m][ks], bf[ks], acc, 0, 0, 0);
#pragma unroll
            for (int i = 0; i < 4; ++i)
                rmax[m][i] = on ? fmaxf(rmax[m][i], acc[i]) : rmax[m][i];
        }
    }

    float s_lo = 0.f, s_hi = 0.f;
#pragma unroll
    for (int m = 0; m < 4; ++m) {
#pragma unroll
        for (int i = 0; i < 4; ++i) {
            float r = rmax[m][i];
            r = fmaxf(r, __shfl_xor(r, 1));
            r = fmaxf(r, __shfl_xor(r, 2));
            r = fmaxf(r, __shfl_xor(r, 4));
            r = fmaxf(r, __shfl_xor(r, 8));
            if (m < 2) s_lo += r; else s_hi += r;
        }
    }
    s_lo += __shfl_xor(s_lo, 16);
    s_lo += __shfl_xor(s_lo, 32);
    s_hi += __shfl_xor(s_hi, 16);
    s_hi += __shfl_xor(s_hi, 32);

    if (lane == 0) {
        const int b_lo = bg * 8 + wave * 2;
        out[(size_t)b_lo * NB + c]       = s_lo;
        out[(size_t)(b_lo + 1) * NB + c] = s_hi;
    }
}

// ---------------------------------------------------------------------------
extern "C" void kernel_launch(void* const* d_in, const int* in_sizes, int n_in,
                              void* d_out, int out_size, void* d_ws, size_t ws_size,
                              hipStream_t stream) {
    const float* Qh = (const float*)d_in[0];
    const float* Dh = (const float*)d_in[1];
    const float* W  = (const float*)d_in[2];
    const unsigned char* dm = (const unsigned char*)d_in[3];
    float* out = (float*)d_out;
    char* ws = (char*)d_ws;

    short*          Wbf   = (short*)(ws + WS_OFF_W);
    unsigned short* maskT = (unsigned short*)(ws + WS_OFF_MASK);
    short*          Qn    = (short*)(ws + WS_OFF_QN);
    short*          Dn    = (short*)(ws + WS_OFF_DN);

    prep<<<97, 256, 0, stream>>>(W, Wbf, dm, maskT);
    proj_norm<<<576, 256, 0, stream>>>(Qh, Dh, Wbf, Qn, Dn);
    maxsim<<<512, 256, 0, stream>>>(Qn, Dn, maskT, out);
}

// Round 5
// 50.363 us; speedup vs baseline: 1.5458x; 1.5458x over previous
//
#include <hip/hip_runtime.h>
#include <hip/hip_bf16.h>
#include <math.h>

typedef __attribute__((ext_vector_type(4))) float f32x4;
typedef __attribute__((ext_vector_type(8))) short bf16x8;

#define NB    64
#define LQ    32
#define LDOC  256
#define HDIM  768
#define DDIM  128
#define NTOK_Q (NB * LQ)        // 2048
#define NTOK_D (NB * LDOC)      // 16384
#define NTOK   (NTOK_Q + NTOK_D) // 18432

// ws layout (bytes):
#define WS_OFF_W    0           // Wbf   : 128*768 bf16   (196608)
#define WS_OFF_MASK 196608      // maskT : 64*16 ushort (2KB)
#define WS_OFF_QN   212992      // Qn    : 2048*128 bf16
#define WS_OFF_DN   737280      // Dn    : 16384*128 bf16

__device__ inline short f2bf(float f) {
    unsigned u = __float_as_uint(f);
    u = (u + 0x7fffu + ((u >> 16) & 1u)) >> 16;   // RNE
    return (short)u;
}

// ---------------------------------------------------------------------------
// prep: blocks 0..95 convert W fp32->bf16; block 96 builds bit-transposed mask.
__global__ void prep(const float* __restrict__ W, short* __restrict__ Wbf,
                     const unsigned char* __restrict__ mraw,
                     unsigned short* __restrict__ maskT) {
    if (blockIdx.x < 96) {
        int i = blockIdx.x * 256 + threadIdx.x;
        float4 v = *(const float4*)(W + (size_t)i * 4);
        short4 o;
        o.x = f2bf(v.x); o.y = f2bf(v.y); o.z = f2bf(v.z); o.w = f2bf(v.w);
        *(short4*)(Wbf + (size_t)i * 4) = o;
        return;
    }
    __shared__ int dword_ok_s;
    if (threadIdx.x == 0) dword_ok_s = 1;
    __syncthreads();
    const unsigned* dw = (const unsigned*)mraw;
    int ok = 1;
    for (int i = threadIdx.x; i < 4096; i += 256) {   // first 16KB: safe both ways
        unsigned v = dw[i];
        if (!(v == 0u || v == 1u || v == 0x3F800000u)) ok = 0;
    }
    if (!ok) atomicAnd(&dword_ok_s, 0);
    __syncthreads();
    const int isdw = dword_ok_s;
    for (int w = threadIdx.x; w < 1024; w += 256) {   // word w: c=w>>4, lane-col=w&15
        const int c = w >> 4, lcc = w & 15;
        unsigned bits = 0;
        if (isdw) {
            for (int nt = 0; nt < 16; ++nt)
                bits |= (dw[c * 256 + nt * 16 + lcc] ? 1u : 0u) << nt;
        } else {
            for (int nt = 0; nt < 16; ++nt)
                bits |= (mraw[c * 256 + nt * 16 + lcc] ? 1u : 0u) << nt;
        }
        maskT[w] = (unsigned short)bits;
    }
}

// ---------------------------------------------------------------------------
// Projection + L2 norm v5: 2-phase global_load_lds GEMM.
// Block = 64 rows x 128 cols, BK=64, 12 K-steps, 4 waves (2x2 of 32x64).
// A staged fp32 (XOR-swizzled source, 16-unit rows), B staged bf16
// (XOR-swizzled source, 8-unit rows); STAGE(t+1) issued before COMPUTE(t),
// single __syncthreads per step drains vmcnt after compute has run.
__global__ __launch_bounds__(256)
void proj_norm(const float* __restrict__ Qh, const float* __restrict__ Dh,
               const short* __restrict__ Wbf,
               short* __restrict__ Qn, short* __restrict__ Dn) {
    const int tid  = threadIdx.x;
    const int lane = tid & 63;
    const int wave = tid >> 6;
    const int g    = lane >> 4;
    const int lc   = lane & 15;
    const int wr   = wave >> 1;          // row-half (32 rows)
    const int wc   = wave & 1;           // col-half (64 cols)
    const int row0 = blockIdx.x * 64;

    const float* Asrc = (row0 < NTOK_Q) ? Qh + (size_t)row0 * HDIM
                                        : Dh + (size_t)(row0 - NTOK_Q) * HDIM;

    __shared__ alignas(16) float As[2][4096];   // [buf][row*64 + unit*4], 16KB each
    __shared__ alignas(16) short Bs[2][8192];   // [buf][n*64 + unit*8],   16KB each
    __shared__ float norms[2][2][32];

    auto STAGE = [&](int buf, int t) {
#pragma unroll
        for (int i = 0; i < 4; ++i) {
            const int sb = i * 256 + wave * 64;          // wave-uniform 16B-slot base
            const int s  = sb + lane;
            const int row = s >> 4;
            const int cu  = (s & 15) ^ (row & 15);       // inverse swizzle on source
            const float* ga = Asrc + (size_t)row * HDIM + t * 64 + cu * 4;
            __builtin_amdgcn_global_load_lds(
                (const __attribute__((address_space(1))) unsigned*)ga,
                (__attribute__((address_space(3))) unsigned*)((char*)&As[buf][0] + (size_t)sb * 16),
                16, 0, 0);
        }
#pragma unroll
        for (int i = 0; i < 4; ++i) {
            const int sb = i * 256 + wave * 64;
            const int s  = sb + lane;
            const int n  = s >> 3;
            const int c8 = (s & 7) ^ (n & 7);
            const short* gb = Wbf + (size_t)n * HDIM + t * 64 + c8 * 8;
            __builtin_amdgcn_global_load_lds(
                (const __attribute__((address_space(1))) unsigned*)gb,
                (__attribute__((address_space(3))) unsigned*)((char*)&Bs[buf][0] + (size_t)sb * 16),
                16, 0, 0);
        }
    };

    f32x4 acc[2][4];
#pragma unroll
    for (int m = 0; m < 2; ++m)
#pragma unroll
        for (int nt = 0; nt < 4; ++nt) acc[m][nt] = (f32x4){0.f, 0.f, 0.f, 0.f};

    STAGE(0, 0);
    __syncthreads();

    for (int t = 0; t < 12; ++t) {
        const int cur = t & 1;
        if (t < 11) STAGE(cur ^ 1, t + 1);     // fly under this step's compute

        const float* Ab = &As[cur][0];
        const short* Bb = &Bs[cur][0];
#pragma unroll
        for (int ks = 0; ks < 2; ++ks) {
            bf16x8 bfr[4];
#pragma unroll
            for (int nt = 0; nt < 4; ++nt) {
                const int nl = wc * 64 + nt * 16 + lc;
                const int c8 = (ks * 4 + g) ^ (nl & 7);    // read-side swizzle
                bfr[nt] = *(const bf16x8*)(Bb + (size_t)nl * 64 + c8 * 8);
            }
#pragma unroll
            for (int m = 0; m < 2; ++m) {
                const int rl = wr * 32 + m * 16 + lc;       // rl & 15 == lc
                const int u0 = (ks * 8 + g * 2) ^ lc;       // read-side swizzle
                const int u1 = (ks * 8 + g * 2 + 1) ^ lc;
                const float4 a0 = *(const float4*)(Ab + (size_t)rl * 64 + u0 * 4);
                const float4 a1 = *(const float4*)(Ab + (size_t)rl * 64 + u1 * 4);
                bf16x8 af;
                af[0] = f2bf(a0.x); af[1] = f2bf(a0.y); af[2] = f2bf(a0.z); af[3] = f2bf(a0.w);
                af[4] = f2bf(a1.x); af[5] = f2bf(a1.y); af[6] = f2bf(a1.z); af[7] = f2bf(a1.w);
#pragma unroll
                for (int nt = 0; nt < 4; ++nt)
                    acc[m][nt] = __builtin_amdgcn_mfma_f32_16x16x32_bf16(af, bfr[nt], acc[m][nt], 0, 0, 0);
            }
        }
        __syncthreads();     // drains vmcnt (next tile landed) + lgkm, then barrier
    }

    // row norms: partial over this wave's 64 cols, combine col-halves via LDS
    float part[2][4];
#pragma unroll
    for (int m = 0; m < 2; ++m)
#pragma unroll
        for (int i = 0; i < 4; ++i) {
            float s = 0.f;
#pragma unroll
            for (int nt = 0; nt < 4; ++nt) s += acc[m][nt][i] * acc[m][nt][i];
            s += __shfl_xor(s, 1);
            s += __shfl_xor(s, 2);
            s += __shfl_xor(s, 4);
            s += __shfl_xor(s, 8);
            part[m][i] = s;
        }
    if (lc == 0) {
#pragma unroll
        for (int m = 0; m < 2; ++m)
#pragma unroll
            for (int i = 0; i < 4; ++i)
                norms[wr][wc][m * 16 + g * 4 + i] = part[m][i];
    }
    __syncthreads();

    short* Obase = (row0 < NTOK_Q) ? Qn + (size_t)row0 * DDIM
                                   : Dn + (size_t)(row0 - NTOK_Q) * DDIM;
#pragma unroll
    for (int m = 0; m < 2; ++m)
#pragma unroll
        for (int i = 0; i < 4; ++i) {
            const int rloc = m * 16 + g * 4 + i;           // within 32-row half
            const float tot = norms[wr][0][rloc] + norms[wr][1][rloc];
            const float inv = 1.f / fmaxf(sqrtf(tot), 1e-12f);
            short* dst = Obase + (size_t)(wr * 32 + rloc) * DDIM + wc * 64;
#pragma unroll
            for (int nt = 0; nt < 4; ++nt)
                dst[nt * 16 + lc] = f2bf(acc[m][nt][i] * inv);
        }
}

// ---------------------------------------------------------------------------
// MaxSim: block = (c, 8 b's) = 256 q-rows x 256 n. D[c] staged once in LDS
// (64KB) via global_load_lds with pre-swizzled source; 4 waves x 256 MFMA.
__global__ __launch_bounds__(256)
void maxsim(const short* __restrict__ Qn, const short* __restrict__ Dn,
            const unsigned short* __restrict__ maskT, float* __restrict__ out) {
    const int x  = blockIdx.x & 7;            // XCD (perf heuristic only)
    const int m8 = (blockIdx.x >> 3) & 7;
    const int bg = blockIdx.x >> 6;           // b-group (8 b's)
    const int c  = x * 8 + m8;                // all 8 bg's of a c on one XCD

    const int wave = threadIdx.x >> 6;
    const int lane = threadIdx.x & 63;
    const int g = lane >> 4, lc = lane & 15;

    __shared__ alignas(16) short Ds[LDOC * DDIM];   // 64KB, swizzled layout

    const short* dsrc = Dn + (size_t)c * LDOC * DDIM;
#pragma unroll
    for (int i = 0; i < 16; ++i) {
        const int slot = wave * 1024 + i * 64 + lane;          // 16B units
        const int row = slot >> 4, c16 = slot & 15;
        const short* gaddr = dsrc + row * DDIM + ((c16 ^ (row & 15)) * 8);
        __builtin_amdgcn_global_load_lds(
            (const __attribute__((address_space(1))) unsigned int*)gaddr,
            (__attribute__((address_space(3))) unsigned int*)(Ds + (size_t)(wave * 1024 + i * 64) * 8),
            16, 0, 0);
    }

    bf16x8 qf[4][4];
    const int qrow0 = bg * 256 + wave * 64;
#pragma unroll
    for (int m = 0; m < 4; ++m) {
        const short* qb = Qn + (size_t)(qrow0 + m * 16 + lc) * DDIM;
#pragma unroll
        for (int ks = 0; ks < 4; ++ks)
            qf[m][ks] = *(const bf16x8*)(qb + ks * 32 + g * 8);
    }

    const unsigned mbits = maskT[c * 16 + lc];    // bit nt = mask[c][nt*16+lc]

    __syncthreads();   // drains vmcnt (staging + q loads) then barrier

    float rmax[4][4];
#pragma unroll
    for (int m = 0; m < 4; ++m)
#pragma unroll
        for (int i = 0; i < 4; ++i) rmax[m][i] = -INFINITY;

    for (int nt = 0; nt < 16; ++nt) {
        bf16x8 bf[4];
        const int row = nt * 16 + lc;
#pragma unroll
        for (int ks = 0; ks < 4; ++ks) {
            const int c16 = (ks * 4 + g) ^ lc;     // read-side swizzle (matches source)
            bf[ks] = *(const bf16x8*)(Ds + row * DDIM + c16 * 8);
        }
        const bool on = (mbits >> nt) & 1;         // n = nt*16+lc == C-col lc
#pragma unroll
        for (int m = 0; m < 4; ++m) {
            f32x4 acc = (f32x4){0.f, 0.f, 0.f, 0.f};
#pragma unroll
            for (int ks = 0; ks < 4; ++ks)
                acc = __builtin_amdgcn_mfma_f32_16x16x32_bf16(qf[m][ks], bf[ks], acc, 0, 0, 0);
#pragma unroll
            for (int i = 0; i < 4; ++i)
                rmax[m][i] = on ? fmaxf(rmax[m][i], acc[i]) : rmax[m][i];
        }
    }

    float s_lo = 0.f, s_hi = 0.f;
#pragma unroll
    for (int m = 0; m < 4; ++m) {
#pragma unroll
        for (int i = 0; i < 4; ++i) {
            float r = rmax[m][i];
            r = fmaxf(r, __shfl_xor(r, 1));
            r = fmaxf(r, __shfl_xor(r, 2));
            r = fmaxf(r, __shfl_xor(r, 4));
            r = fmaxf(r, __shfl_xor(r, 8));
            if (m < 2) s_lo += r; else s_hi += r;
        }
    }
    s_lo += __shfl_xor(s_lo, 16);
    s_lo += __shfl_xor(s_lo, 32);
    s_hi += __shfl_xor(s_hi, 16);
    s_hi += __shfl_xor(s_hi, 32);

    if (lane == 0) {
        const int b_lo = bg * 8 + wave * 2;
        out[(size_t)b_lo * NB + c]       = s_lo;
        out[(size_t)(b_lo + 1) * NB + c] = s_hi;
    }
}

// ---------------------------------------------------------------------------
extern "C" void kernel_launch(void* const* d_in, const int* in_sizes, int n_in,
                              void* d_out, int out_size, void* d_ws, size_t ws_size,
                              hipStream_t stream) {
    const float* Qh = (const float*)d_in[0];
    const float* Dh = (const float*)d_in[1];
    const float* W  = (const float*)d_in[2];
    const unsigned char* dm = (const unsigned char*)d_in[3];
    float* out = (float*)d_out;
    char* ws = (char*)d_ws;

    short*          Wbf   = (short*)(ws + WS_OFF_W);
    unsigned short* maskT = (unsigned short*)(ws + WS_OFF_MASK);
    short*          Qn    = (short*)(ws + WS_OFF_QN);
    short*          Dn    = (short*)(ws + WS_OFF_DN);

    prep<<<97, 256, 0, stream>>>(W, Wbf, dm, maskT);
    proj_norm<<<NTOK / 64, 256, 0, stream>>>(Qh, Dh, Wbf, Qn, Dn);
    maxsim<<<512, 256, 0, stream>>>(Qn, Dn, maskT, out);
}

// Round 6
// 42.626 us; speedup vs baseline: 1.8264x; 1.1815x over previous
//
#include <hip/hip_runtime.h>
#include <hip/hip_bf16.h>
#include <math.h>

typedef __attribute__((ext_vector_type(4))) float f32x4;
typedef __attribute__((ext_vector_type(8))) short bf16x8;

#define NB    64
#define LQ    32
#define LDOC  256
#define HDIM  768
#define DDIM  128
#define NTOK_Q (NB * LQ)        // 2048
#define NTOK_D (NB * LDOC)      // 16384
#define NTOK   (NTOK_Q + NTOK_D) // 18432

// ws layout (bytes):
#define WS_OFF_W    0           // Wbf   : 128*768 bf16   (196608)
#define WS_OFF_MASK 196608      // maskT : 64*16 ushort (2KB)
#define WS_OFF_QN   212992      // Qn    : 2048*128 bf16
#define WS_OFF_DN   737280      // Dn    : 16384*128 bf16

__device__ inline short f2bf(float f) {
    unsigned u = __float_as_uint(f);
    u = (u + 0x7fffu + ((u >> 16) & 1u)) >> 16;   // RNE
    return (short)u;
}

// ---------------------------------------------------------------------------
// prep: blocks 0..95 convert W fp32->bf16; block 96 builds bit-transposed mask.
__global__ void prep(const float* __restrict__ W, short* __restrict__ Wbf,
                     const unsigned char* __restrict__ mraw,
                     unsigned short* __restrict__ maskT) {
    if (blockIdx.x < 96) {
        int i = blockIdx.x * 256 + threadIdx.x;
        float4 v = *(const float4*)(W + (size_t)i * 4);
        short4 o;
        o.x = f2bf(v.x); o.y = f2bf(v.y); o.z = f2bf(v.z); o.w = f2bf(v.w);
        *(short4*)(Wbf + (size_t)i * 4) = o;
        return;
    }
    __shared__ int dword_ok_s;
    if (threadIdx.x == 0) dword_ok_s = 1;
    __syncthreads();
    const unsigned* dw = (const unsigned*)mraw;
    int ok = 1;
    for (int i = threadIdx.x; i < 4096; i += 256) {   // first 16KB: safe both ways
        unsigned v = dw[i];
        if (!(v == 0u || v == 1u || v == 0x3F800000u)) ok = 0;
    }
    if (!ok) atomicAnd(&dword_ok_s, 0);
    __syncthreads();
    const int isdw = dword_ok_s;
    for (int w = threadIdx.x; w < 1024; w += 256) {   // word w: c=w>>4, lane-col=w&15
        const int c = w >> 4, lcc = w & 15;
        unsigned bits = 0;
        if (isdw) {
            for (int nt = 0; nt < 16; ++nt)
                bits |= (dw[c * 256 + nt * 16 + lcc] ? 1u : 0u) << nt;
        } else {
            for (int nt = 0; nt < 16; ++nt)
                bits |= (mraw[c * 256 + nt * 16 + lcc] ? 1u : 0u) << nt;
        }
        maskT[w] = (unsigned short)bits;
    }
}

// ---------------------------------------------------------------------------
// Projection + L2 norm v6: 2-phase global_load_lds GEMM, sized for TLP.
// Block = 32 rows x 128 cols, BK=64, 12 steps, 4 waves (2 row-halves x 2
// col-halves, each 16x64). LDS 48KB -> 3 blocks/CU; 576 blocks co-resident.
__global__ __launch_bounds__(256)
void proj_norm(const float* __restrict__ Qh, const float* __restrict__ Dh,
               const short* __restrict__ Wbf,
               short* __restrict__ Qn, short* __restrict__ Dn) {
    const int tid  = threadIdx.x;
    const int lane = tid & 63;
    const int wave = tid >> 6;
    const int g    = lane >> 4;
    const int lc   = lane & 15;
    const int wr   = wave >> 1;          // 16-row half
    const int wc   = wave & 1;           // 64-col half
    const int row0 = blockIdx.x * 32;

    const float* Asrc = (row0 < NTOK_Q) ? Qh + (size_t)row0 * HDIM
                                        : Dh + (size_t)(row0 - NTOK_Q) * HDIM;

    __shared__ alignas(16) float As[2][2048];   // [buf][row*64 + unit*4], 8KB each
    __shared__ alignas(16) short Bs[2][8192];   // [buf][n*64 + unit*8],  16KB each
    __shared__ float norms[2][2][16];

    auto STAGE = [&](int buf, int t) {
#pragma unroll
        for (int i = 0; i < 2; ++i) {            // A: 32 rows x 16 units = 512 slots
            const int sb = i * 256 + wave * 64;  // wave-uniform 16B-slot base
            const int s  = sb + lane;
            const int row = s >> 4;
            const int cu  = (s & 15) ^ (row & 15);       // inverse swizzle on source
            const float* ga = Asrc + (size_t)row * HDIM + t * 64 + cu * 4;
            __builtin_amdgcn_global_load_lds(
                (const __attribute__((address_space(1))) unsigned*)ga,
                (__attribute__((address_space(3))) unsigned*)((char*)&As[buf][0] + (size_t)sb * 16),
                16, 0, 0);
        }
#pragma unroll
        for (int i = 0; i < 4; ++i) {            // B: 128 n x 8 units = 1024 slots
            const int sb = i * 256 + wave * 64;
            const int s  = sb + lane;
            const int n  = s >> 3;
            const int c8 = (s & 7) ^ (n & 7);
            const short* gb = Wbf + (size_t)n * HDIM + t * 64 + c8 * 8;
            __builtin_amdgcn_global_load_lds(
                (const __attribute__((address_space(1))) unsigned*)gb,
                (__attribute__((address_space(3))) unsigned*)((char*)&Bs[buf][0] + (size_t)sb * 16),
                16, 0, 0);
        }
    };

    f32x4 acc[4];
#pragma unroll
    for (int nt = 0; nt < 4; ++nt) acc[nt] = (f32x4){0.f, 0.f, 0.f, 0.f};

    STAGE(0, 0);
    __syncthreads();

    for (int t = 0; t < 12; ++t) {
        const int cur = t & 1;
        if (t < 11) STAGE(cur ^ 1, t + 1);     // fly under this step's compute

        const float* Ab = &As[cur][0];
        const short* Bb = &Bs[cur][0];
#pragma unroll
        for (int ks = 0; ks < 2; ++ks) {
            bf16x8 bfr[4];
#pragma unroll
            for (int nt = 0; nt < 4; ++nt) {
                const int nl = wc * 64 + nt * 16 + lc;
                const int c8 = (ks * 4 + g) ^ (nl & 7);    // read-side swizzle
                bfr[nt] = *(const bf16x8*)(Bb + (size_t)nl * 64 + c8 * 8);
            }
            const int rl = wr * 16 + lc;                   // rl & 15 == lc
            const int u0 = (ks * 8 + g * 2) ^ lc;          // read-side swizzle
            const int u1 = (ks * 8 + g * 2 + 1) ^ lc;
            const float4 a0 = *(const float4*)(Ab + (size_t)rl * 64 + u0 * 4);
            const float4 a1 = *(const float4*)(Ab + (size_t)rl * 64 + u1 * 4);
            bf16x8 af;
            af[0] = f2bf(a0.x); af[1] = f2bf(a0.y); af[2] = f2bf(a0.z); af[3] = f2bf(a0.w);
            af[4] = f2bf(a1.x); af[5] = f2bf(a1.y); af[6] = f2bf(a1.z); af[7] = f2bf(a1.w);
#pragma unroll
            for (int nt = 0; nt < 4; ++nt)
                acc[nt] = __builtin_amdgcn_mfma_f32_16x16x32_bf16(af, bfr[nt], acc[nt], 0, 0, 0);
        }
        __syncthreads();     // drains vmcnt (next tile landed), then barrier
    }

    // row norms: partial over this wave's 64 cols, combine col-halves via LDS
    float part[4];
#pragma unroll
    for (int i = 0; i < 4; ++i) {
        float s = 0.f;
#pragma unroll
        for (int nt = 0; nt < 4; ++nt) s += acc[nt][i] * acc[nt][i];
        s += __shfl_xor(s, 1);
        s += __shfl_xor(s, 2);
        s += __shfl_xor(s, 4);
        s += __shfl_xor(s, 8);
        part[i] = s;
    }
    if (lc == 0) {
#pragma unroll
        for (int i = 0; i < 4; ++i) norms[wr][wc][g * 4 + i] = part[i];
    }
    __syncthreads();

    short* Obase = (row0 < NTOK_Q) ? Qn + (size_t)row0 * DDIM
                                   : Dn + (size_t)(row0 - NTOK_Q) * DDIM;
#pragma unroll
    for (int i = 0; i < 4; ++i) {
        const int rloc = g * 4 + i;                     // within 16-row tile
        const float tot = norms[wr][0][rloc] + norms[wr][1][rloc];
        const float inv = 1.f / fmaxf(sqrtf(tot), 1e-12f);
        short* dst = Obase + (size_t)(wr * 16 + rloc) * DDIM + wc * 64;
#pragma unroll
        for (int nt = 0; nt < 4; ++nt)
            dst[nt * 16 + lc] = f2bf(acc[nt][i] * inv);
    }
}

// ---------------------------------------------------------------------------
// MaxSim v4: block = (c, 8 b's), 8 waves; wave <-> one b (32 q-rows x 256 n).
// D[c] staged in 4 chunks of 64 rows, double-buffered (32KB LDS), XOR-swizzled
// source + read. stage(ch+1) flies under compute(ch); no cross-wave reduce.
__global__ __launch_bounds__(512)
void maxsim(const short* __restrict__ Qn, const short* __restrict__ Dn,
            const unsigned short* __restrict__ maskT, float* __restrict__ out) {
    const int x  = blockIdx.x & 7;            // XCD (perf heuristic only)
    const int m8 = (blockIdx.x >> 3) & 7;
    const int bg = blockIdx.x >> 6;           // b-group (8 b's)
    const int c  = x * 8 + m8;                // all 8 bg's of a c on one XCD

    const int wave = threadIdx.x >> 6;        // 0..7  <-> local b
    const int lane = threadIdx.x & 63;
    const int g = lane >> 4, lc = lane & 15;

    __shared__ alignas(16) short Ds[2][4096 * 2];   // [buf][64 rows * 128], 16KB each

    const short* dsrc = Dn + (size_t)c * LDOC * DDIM;

    auto STAGE = [&](int buf, int ch) {
#pragma unroll
        for (int i = 0; i < 2; ++i) {            // 64 rows x 8 slots... 1024 slots/8w
            const int sb = wave * 128 + i * 64;  // wave-uniform 16B-slot base
            const int s  = sb + lane;
            const int rowl = s >> 4;             // 0..63
            const int c16  = (s & 15) ^ (rowl & 15);
            const short* ga = dsrc + (size_t)(ch * 64 + rowl) * DDIM + c16 * 8;
            __builtin_amdgcn_global_load_lds(
                (const __attribute__((address_space(1))) unsigned*)ga,
                (__attribute__((address_space(3))) unsigned*)((char*)&Ds[buf][0] + (size_t)sb * 16),
                16, 0, 0);
        }
    };

    STAGE(0, 0);

    // Q fragments: this wave's 32 q-rows (one b), full K=128
    bf16x8 qf[2][4];
    const int qrow0 = bg * 256 + wave * 32;
#pragma unroll
    for (int m = 0; m < 2; ++m) {
        const short* qb = Qn + (size_t)(qrow0 + m * 16 + lc) * DDIM;
#pragma unroll
        for (int ks = 0; ks < 4; ++ks)
            qf[m][ks] = *(const bf16x8*)(qb + ks * 32 + g * 8);
    }
    const unsigned mbits = maskT[c * 16 + lc];    // bit nt = mask[c][nt*16+lc]

    __syncthreads();   // chunk 0 landed

    float rmax[2][4];
#pragma unroll
    for (int m = 0; m < 2; ++m)
#pragma unroll
        for (int i = 0; i < 4; ++i) rmax[m][i] = -INFINITY;

    for (int ch = 0; ch < 4; ++ch) {
        const int buf = ch & 1;
        if (ch < 3) STAGE(buf ^ 1, ch + 1);       // fly under this chunk's compute
        const short* Db = &Ds[buf][0];
#pragma unroll
        for (int j = 0; j < 4; ++j) {
            const int rowl = j * 16 + lc;
            bf16x8 bf[4];
#pragma unroll
            for (int ks = 0; ks < 4; ++ks) {
                const int c16 = (ks * 4 + g) ^ lc;     // read-side swizzle
                bf[ks] = *(const bf16x8*)(Db + (size_t)rowl * DDIM + c16 * 8);
            }
            const bool on = (mbits >> (ch * 4 + j)) & 1;
#pragma unroll
            for (int m = 0; m < 2; ++m) {
                f32x4 acc = (f32x4){0.f, 0.f, 0.f, 0.f};
#pragma unroll
                for (int ks = 0; ks < 4; ++ks)
                    acc = __builtin_amdgcn_mfma_f32_16x16x32_bf16(qf[m][ks], bf[ks], acc, 0, 0, 0);
#pragma unroll
                for (int i = 0; i < 4; ++i)
                    rmax[m][i] = on ? fmaxf(rmax[m][i], acc[i]) : rmax[m][i];
            }
        }
        __syncthreads();   // next chunk landed; this chunk's reads done block-wide
    }

    // cross-col max (16 lc lanes), then sum this wave's 32 rows
    float s = 0.f;
#pragma unroll
    for (int m = 0; m < 2; ++m)
#pragma unroll
        for (int i = 0; i < 4; ++i) {
            float r = rmax[m][i];
            r = fmaxf(r, __shfl_xor(r, 1));
            r = fmaxf(r, __shfl_xor(r, 2));
            r = fmaxf(r, __shfl_xor(r, 4));
            r = fmaxf(r, __shfl_xor(r, 8));
            s += r;
        }
    s += __shfl_xor(s, 16);
    s += __shfl_xor(s, 32);

    if (lane == 0) {
        const int b = bg * 8 + wave;
        out[(size_t)b * NB + c] = s;
    }
}

// ---------------------------------------------------------------------------
extern "C" void kernel_launch(void* const* d_in, const int* in_sizes, int n_in,
                              void* d_out, int out_size, void* d_ws, size_t ws_size,
                              hipStream_t stream) {
    const float* Qh = (const float*)d_in[0];
    const float* Dh = (const float*)d_in[1];
    const float* W  = (const float*)d_in[2];
    const unsigned char* dm = (const unsigned char*)d_in[3];
    float* out = (float*)d_out;
    char* ws = (char*)d_ws;

    short*          Wbf   = (short*)(ws + WS_OFF_W);
    unsigned short* maskT = (unsigned short*)(ws + WS_OFF_MASK);
    short*          Qn    = (short*)(ws + WS_OFF_QN);
    short*          Dn    = (short*)(ws + WS_OFF_DN);

    prep<<<97, 256, 0, stream>>>(W, Wbf, dm, maskT);
    proj_norm<<<NTOK / 32, 256, 0, stream>>>(Qh, Dh, Wbf, Qn, Dn);
    maxsim<<<512, 512, 0, stream>>>(Qn, Dn, maskT, out);
}